// Round 6
// baseline (596.874 us; speedup 1.0000x reference)
//
#include <hip/hip_runtime.h>

typedef unsigned short u16;
typedef unsigned int u32;
typedef __attribute__((ext_vector_type(8))) short bf16x8;
typedef __attribute__((ext_vector_type(4))) float f32x4;

#define NTOK 65536
#define DM 512
#define DI 1024

__device__ __forceinline__ float bf2f(u16 u){ u32 x=((u32)u)<<16; float f; __builtin_memcpy(&f,&x,4); return f; }
__device__ __forceinline__ u16 f2bf(float f){ u32 u; __builtin_memcpy(&u,&f,4); u += 0x7fffu + ((u>>16)&1u); return (u16)(u>>16); }
__device__ __forceinline__ float siluf(float x){ return x/(1.f+__expf(-x)); }
// fast softplus: log(1+e^x) via HW exp/log; guard matches reference large-x behavior
__device__ __forceinline__ float softplus_fast(float x){
  float l = __logf(1.f + __expf(x));
  return (x > 20.f) ? x : l;
}

__device__ __forceinline__ void gload_lds16(const void* g, void* l){
  __builtin_amdgcn_global_load_lds((const __attribute__((address_space(1))) u32*)g,
                                   (__attribute__((address_space(3))) u32*)l, 16, 0, 0);
}

__global__ void k_sentinel(float* out){ out[0] = 1.2345e6f; }

__global__ void k_cast_bf16(const float* __restrict__ in, u16* __restrict__ out, int n){
  int i = (blockIdx.x*256 + threadIdx.x)*4;
  if (i >= n) return;
  float4 v = *(const float4*)(in + i);
  ushort4 o; o.x=f2bf(v.x); o.y=f2bf(v.y); o.z=f2bf(v.z); o.w=f2bf(v.w);
  *(ushort4*)(out + i) = o;
}

// W_a[i][j] = sum_c fc_w[i][c] * out_proj_w[c][j], padded to 64 rows (zeros), bf16
__global__ void k_make_wa(const float* __restrict__ fcw, const float* __restrict__ opw,
                          u16* __restrict__ wa){
  int j = blockIdx.x*256 + threadIdx.x;   // 0..1023
  int i = blockIdx.y;                     // 0..63
  float s = 0.f;
  if (i < 36){
    const float* fr = fcw + i*DM;
    #pragma unroll 8
    for (int k=0;k<DM;++k) s += fr[k]*opw[(size_t)k*DI + j];
  }
  wa[(size_t)i*DI + j] = f2bf(s);
}

// xz = f @ in_proj^T. 128x256 tile, BK=32, 512 thr (8 waves, 64x64 each), dbuf 48KB,
// chunk-transposed LDS [kchunk][row] (conflict-free frag reads), XCD-grouped grid.
// grid 4096: d&7 = XCD, q=d>>3: row-group g = xcd+8*(q>>3), col-block cb = q&7.
__global__ __launch_bounds__(512) void k_gemm_xz(
  const u16* __restrict__ A, const u16* __restrict__ B,
  const float* __restrict__ convw, const float* __restrict__ convb,
  u16* __restrict__ xp, u16* __restrict__ zs)
{
  __shared__ u16 smem[24576];            // 48 KB: buf*(A 4096 | B 8192)
  const int tid=threadIdx.x, wv=tid>>6, ln=tid&63;
  const int l15=ln&15, l4=ln>>4;
  const int d=blockIdx.x, xcd=d&7, q=d>>3;
  const int g = xcd + 8*(q>>3);          // 0..511 row-group (bijective)
  const int cb = q & 7;                  // 0..7 col-block
  const int r0 = g*128, c0 = cb*256;
  const int wm=wv>>2, wn=wv&3;           // 2M x 4N waves, wave tile 64x64
  f32x4 acc[4][4]={};

  // staging source addresses (chunk-transposed LDS layout via global permutation)
  const int arow=(wv&1)*64+ln, achk=wv>>1;          // A: thread t -> row t&127, chunk t>>7
  const int brow=(wv&3)*64+ln, bch=wv>>2;           // B: per g: row t&255, chunk g*2+(wv>>2)
  const u16* Ag  = A + (size_t)(r0+arow)*DM + achk*8;
  const u16* Bg0 = B + (size_t)(c0+brow)*DM + (bch+0)*8;
  const u16* Bg1 = B + (size_t)(c0+brow)*DM + (bch+2)*8;
  const int ldsA = wv*512;                           // u16 offsets within buf
  const int ldsB0 = wv*512, ldsB1 = 4096 + wv*512;

  auto STAGE=[&](int buf, int kt){
    const int k0 = kt*32;
    u16* Ad = smem + buf*12288;
    u16* Bd = Ad + 4096;
    gload_lds16(Ag  + k0, Ad + ldsA);
    gload_lds16(Bg0 + k0, Bd + ldsB0);
    gload_lds16(Bg1 + k0, Bd + ldsB1);
  };

  // fragment read offsets (loop-invariant): A [chunk][row]: chunk*1024+row*8; B: chunk*2048+row*8
  int offA[4], offB[4];
  #pragma unroll
  for (int m=0;m<4;++m) offA[m] = l4*1024 + (wm*64 + m*16 + l15)*8;
  #pragma unroll
  for (int n=0;n<4;++n) offB[n] = l4*2048 + (wn*64 + n*16 + l15)*8;

  STAGE(0,0);
  __syncthreads();
  __builtin_amdgcn_sched_barrier(0);
  #pragma clang loop unroll(disable)
  for (int t=0;t<16;++t){
    if (t<15) STAGE((t+1)&1, t+1);
    const u16* Ac = smem + (t&1)*12288;
    const u16* Bc = Ac + 4096;
    bf16x8 af[4], bfr[4];
    #pragma unroll
    for (int m=0;m<4;++m) af[m]=*(const bf16x8*)(Ac + offA[m]);
    #pragma unroll
    for (int n=0;n<4;++n) bfr[n]=*(const bf16x8*)(Bc + offB[n]);
    #pragma unroll
    for (int m=0;m<4;++m)
      #pragma unroll
      for (int n=0;n<4;++n)
        acc[m][n]=__builtin_amdgcn_mfma_f32_16x16x32_bf16(af[m],bfr[n],acc[m][n],0,0,0);
    __syncthreads();
    __builtin_amdgcn_sched_barrier(0);
  }

  // Epilogue: two half-restages of 128 cols through W[128][136] (stride 272B, ~conflict-free)
  const bool isx = (c0 < DI);
  u16* W = smem;
  #pragma unroll
  for (int ch=0; ch<2; ++ch){
    if ((wn>>1) == ch){
      #pragma unroll
      for (int n=0;n<4;++n){
        int tcol = (wn&1)*64 + n*16 + l15;          // 0..127 within half
        int gcol = c0 + ch*128 + tcol;
        float cw = isx ? convw[gcol*4+3] : 0.f;
        float cbv= isx ? convb[gcol]     : 0.f;
        #pragma unroll
        for (int m=0;m<4;++m){
          int trow = wm*64 + m*16 + l4*4;
          #pragma unroll
          for (int r=0;r<4;++r){
            float v = acc[m][n][r];
            float o = isx ? siluf(v*cw + cbv) : siluf(v);
            W[(trow+r)*136 + tcol] = f2bf(o);
          }
        }
      }
    }
    __syncthreads();
    const int orow = tid>>2, qq = tid&3;
    const u16* sp = W + orow*136 + qq*32;
    const int gcol0 = c0 + ch*128 + qq*32;
    u16* dst = (isx ? xp : zs) + (size_t)(r0+orow)*DI + (isx ? gcol0 : gcol0 - DI);
    #pragma unroll
    for (int j=0;j<2;++j)
      ((int4*)dst)[j] = ((const int4*)sp)[j];
    ((int4*)dst)[0+0] = ((const int4*)sp)[0];
    ((int4*)dst)[1] = ((const int4*)sp)[1];
    ((int4*)dst)[2] = ((const int4*)sp)[2];
    ((int4*)dst)[3] = ((const int4*)sp)[3];
    __syncthreads();
  }
}

// 128-row tile x K=1024 GEMM against 64-row B, dbuf + swizzle.
// EPI=0: fused x_dbl epilogue -> dtb(bf16) + bc. EPI=1: out[t*36+j]=acc+fcb[j] (j<36)
template<int EPI>
__global__ __launch_bounds__(256) void k_gemm_n64(
  const u16* __restrict__ A, const u16* __restrict__ B,
  u16* __restrict__ dtb, float* __restrict__ bc,
  const float* __restrict__ fcb, float* __restrict__ out)
{
  __shared__ u16 smem[24576];             // 48 KB: As0|As1 (8192 each) | Bs0|Bs1 (4096 each)
  u16* SA = smem;
  u16* SB = smem + 16384;                 // +buf*4096
  const int tid=threadIdx.x, wv=tid>>6, ln=tid&63;
  const int l15=ln&15, l4=ln>>4, h=l15&7;
  const int r0=blockIdx.x*128;
  const int wm=wv>>1, wn=wv&1;
  const int sr=ln>>3, scs=((ln&7)^sr)*8;
  const int chk0=(l4^h)*8, chk1=((l4+4)^h)*8;
  const int rA=(wm*64+l15)*64, rB=(wn*32+l15)*64;
  f32x4 acc[4][2]={};

  auto STAGE=[&](int buf, int k0){
    u16* Ad = SA + buf*8192;
    u16* Bd = SB + buf*4096;
    #pragma unroll
    for (int it=0;it<4;++it){
      int c=wv*4+it;
      gload_lds16(A + (size_t)(r0 + c*8 + sr)*DI + k0 + scs, Ad + c*512);
    }
    #pragma unroll
    for (int it=0;it<2;++it){
      int c=wv*2+it;
      gload_lds16(B + (size_t)(c*8 + sr)*DI + k0 + scs, Bd + c*512);
    }
  };

  STAGE(0, 0);
  __syncthreads();
  __builtin_amdgcn_sched_barrier(0);
  int cur = 0;
  #pragma clang loop unroll(disable)
  for (int t=0;t<16;++t){
    if (t < 15) STAGE(cur^1, (t+1)*64);
    const u16* Ac = SA + cur*8192;
    const u16* Bc = SB + cur*4096;
    #pragma unroll
    for (int kk=0;kk<2;++kk){
      const int ch = kk ? chk1 : chk0;
      bf16x8 af[4], bfr[2];
      #pragma unroll
      for (int m=0;m<4;++m) af[m]=*(const bf16x8*)(Ac + rA + m*1024 + ch);
      #pragma unroll
      for (int n=0;n<2;++n) bfr[n]=*(const bf16x8*)(Bc + rB + n*1024 + ch);
      #pragma unroll
      for (int m=0;m<4;++m)
        #pragma unroll
        for (int n=0;n<2;++n)
          acc[m][n]=__builtin_amdgcn_mfma_f32_16x16x32_bf16(af[m],bfr[n],acc[m][n],0,0,0);
    }
    __syncthreads();
    __builtin_amdgcn_sched_barrier(0);
    cur ^= 1;
  }

  if (EPI==0){
    // restage fp32 x_dbl tile [128][68] -> emit dtb (cols 0..31, bf16) + bc (sum B*C)
    float* W = (float*)smem;
    #pragma unroll
    for (int n=0;n<2;++n){
      int j = wn*32 + n*16 + l15;
      #pragma unroll
      for (int m=0;m<4;++m){
        int trow = wm*64 + m*16 + l4*4;
        #pragma unroll
        for (int r=0;r<4;++r)
          W[(trow+r)*68 + j] = acc[m][n][r];
      }
    }
    __syncthreads();
    const int row = tid>>1, half = tid&1;
    const float* wr = W + row*68;
    if (half==0){
      u16* dst = dtb + (size_t)(r0+row)*32;
      #pragma unroll
      for (int qv=0;qv<4;++qv){
        bf16x8 o;
        #pragma unroll
        for (int e=0;e<8;++e) o[e] = (short)f2bf(wr[qv*8+e]);
        *(bf16x8*)(dst + qv*8) = o;
      }
    } else {
      float s=0.f;
      #pragma unroll
      for (int e=0;e<16;++e) s += wr[32+e]*wr[48+e];
      bc[r0+row] = s;
    }
  } else {
    #pragma unroll
    for (int n=0;n<2;++n){
      int j = wn*32 + n*16 + l15;   // 0..63
      #pragma unroll
      for (int m=0;m<4;++m){
        #pragma unroll
        for (int r=0;r<4;++r){
          int t = r0 + wm*64 + m*16 + l4*4 + r;
          if (j < 36) out[(size_t)t*36 + j] = acc[m][n][r] + fcb[j];
        }
      }
    }
  }
}

// delta GEMM (K=32) + fused w=softplus*bc+D in-fragment, LDS-restaged (bf16) epilogue:
// vectorized xp/zy int4 loads, y stored int4 in place. grid (8, 512).
__global__ __launch_bounds__(256) void k_delta_y(
  const u16* __restrict__ dtb, const u16* __restrict__ Bw,
  const float* __restrict__ dpb, const float* __restrict__ Dv,
  const float* __restrict__ bc,
  const u16* __restrict__ xp, u16* __restrict__ zy)
{
  __shared__ u16 smem[17408];            // 34.8 KB: GEMM phase As(4096)|Bs(4096); epi phase W[128][136]
  u16* As = smem;
  u16* Bs = smem + 4096;
  const int tid=threadIdx.x, wv=tid>>6, ln=tid&63;
  const int l15=ln&15, l4=ln>>4;
  const int c0=blockIdx.x*128, r0=blockIdx.y*128;
  const int wm=wv>>1, wn=wv&1;
  const int sr=ln>>2, sc=(ln&3)*8;   // 16 rows/chunk, 4 lanes/row
  #pragma unroll
  for (int it=0;it<2;++it){
    int c=wv*2+it;
    gload_lds16(dtb + (size_t)(r0 + c*16 + sr)*32 + sc, As + c*512);
  }
  #pragma unroll
  for (int it=0;it<2;++it){
    int c=wv*2+it;
    gload_lds16(Bw + (size_t)(c0 + c*16 + sr)*32 + sc, Bs + c*512);
  }
  __syncthreads();
  __builtin_amdgcn_sched_barrier(0);
  f32x4 acc[4][4]={};
  bf16x8 af[4], bfr[4];
  #pragma unroll
  for (int m=0;m<4;++m) af[m]=*(const bf16x8*)(As + (wm*64+m*16+l15)*32 + l4*8);
  #pragma unroll
  for (int n=0;n<4;++n) bfr[n]=*(const bf16x8*)(Bs + (wn*64+n*16+l15)*32 + l4*8);
  #pragma unroll
  for (int m=0;m<4;++m)
    #pragma unroll
    for (int n=0;n<4;++n)
      acc[m][n]=__builtin_amdgcn_mfma_f32_16x16x32_bf16(af[m],bfr[n],acc[m][n],0,0,0);
  __syncthreads();   // all waves done reading As/Bs before W overwrites them
  // in-fragment: w = softplus(acc + dpb[j]) * bc[t] + D[j], restage bf16 to W[128][136]
  u16* W = smem;
  #pragma unroll
  for (int n=0;n<4;++n){
    int tcol = wn*64 + n*16 + l15;
    int j = c0 + tcol;
    float dpbj = dpb[j], Dj = Dv[j];
    #pragma unroll
    for (int m=0;m<4;++m){
      int trow = wm*64 + m*16 + l4*4;
      #pragma unroll
      for (int r=0;r<4;++r){
        float delta = softplus_fast(acc[m][n][r] + dpbj);
        float w = delta*bc[r0 + trow + r] + Dj;
        W[(trow+r)*136 + tcol] = f2bf(w);
      }
    }
  }
  __syncthreads();
  // vectorized finish: each thread owns a contiguous 64-col half-row
  const int row = tid>>1, half = tid&1;
  const u16* wp = W + row*136 + half*64;
  const size_t gbase = (size_t)(r0 + row)*DI + c0 + half*64;
  const u16* xpp = xp + gbase;
  u16* zp = zy + gbase;
  #pragma unroll
  for (int q=0;q<8;++q){
    bf16x8 wv8 = *(const bf16x8*)(wp + q*8);
    bf16x8 xv  = *(const bf16x8*)(xpp + q*8);
    bf16x8 zv  = *(const bf16x8*)(zp + q*8);
    bf16x8 ov;
    #pragma unroll
    for (int e=0;e<8;++e){
      float y = bf2f((u16)wv8[e]) * bf2f((u16)xv[e]) * bf2f((u16)zv[e]);
      ov[e] = (short)f2bf(y);
    }
    *(bf16x8*)(zp + q*8) = ov;
  }
}

extern "C" void kernel_launch(void* const* d_in, const int* in_sizes, int n_in,
                              void* d_out, int out_size, void* d_ws, size_t ws_size,
                              hipStream_t stream){
  const float* f      = (const float*)d_in[0];
  const float* inpw   = (const float*)d_in[1];
  const float* convw  = (const float*)d_in[2];
  const float* convb  = (const float*)d_in[3];
  const float* xprojw = (const float*)d_in[4];
  const float* dtpw   = (const float*)d_in[5];
  const float* dtpb   = (const float*)d_in[6];
  const float* Dv     = (const float*)d_in[8];
  const float* opw    = (const float*)d_in[9];
  const float* fcw    = (const float*)d_in[10];
  const float* fcb    = (const float*)d_in[11];
  float* out = (float*)d_out;

  char* ws = (char*)d_ws;
  size_t off = 0;
  auto alloc = [&](size_t sz)->void*{ void* p = ws + off; off += (sz + 255) & ~(size_t)255; return p; };
  u16*   fbf = (u16*)  alloc((size_t)NTOK*DM*2);
  u16*   xp  = (u16*)  alloc((size_t)NTOK*DI*2);
  u16*   zy  = (u16*)  alloc((size_t)NTOK*DI*2);
  u16*   dtb = (u16*)  alloc((size_t)NTOK*32*2);
  float* bc  = (float*)alloc((size_t)NTOK*4);
  u16*   ipw = (u16*)  alloc((size_t)2048*512*2);
  u16*   xpw = (u16*)  alloc((size_t)64*1024*2);
  u16*   dpw = (u16*)  alloc((size_t)1024*32*2);
  u16*   wa  = (u16*)  alloc((size_t)64*1024*2);
  if (off > ws_size){ k_sentinel<<<1,1,0,stream>>>(out); return; }

  k_cast_bf16<<<dim3((NTOK*DM/4)/256),256,0,stream>>>(f, fbf, NTOK*DM);
  k_cast_bf16<<<dim3((2048*512/4)/256),256,0,stream>>>(inpw, ipw, 2048*512);
  k_cast_bf16<<<dim3((64*1024/4)/256),256,0,stream>>>(xprojw, xpw, 64*1024);
  k_cast_bf16<<<dim3((1024*32/4)/256),256,0,stream>>>(dtpw, dpw, 1024*32);
  k_make_wa<<<dim3(4,64),256,0,stream>>>(fcw, opw, wa);

  k_gemm_xz<<<dim3(4096),512,0,stream>>>(fbf, ipw, convw, convb, xp, zy);
  k_gemm_n64<0><<<dim3(512),256,0,stream>>>(xp, xpw, dtb, bc, nullptr, nullptr);
  k_delta_y<<<dim3(8,512),256,0,stream>>>(dtb, dpw, dtpb, Dv, bc, xp, zy);
  k_gemm_n64<1><<<dim3(512),256,0,stream>>>(zy, wa, nullptr, nullptr, fcb, out);
}

// Round 7
// 555.802 us; speedup vs baseline: 1.0739x; 1.0739x over previous
//
#include <hip/hip_runtime.h>

typedef unsigned short u16;
typedef unsigned int u32;
typedef __attribute__((ext_vector_type(8))) short bf16x8;
typedef __attribute__((ext_vector_type(4))) float f32x4;

#define NTOK 65536
#define DM 512
#define DI 1024

__device__ __forceinline__ float bf2f(u16 u){ u32 x=((u32)u)<<16; float f; __builtin_memcpy(&f,&x,4); return f; }
__device__ __forceinline__ u16 f2bf(float f){ u32 u; __builtin_memcpy(&u,&f,4); u += 0x7fffu + ((u>>16)&1u); return (u16)(u>>16); }
__device__ __forceinline__ float siluf(float x){ return x/(1.f+__expf(-x)); }
// fast softplus: log(1+e^x) via HW exp/log; guard matches reference large-x behavior
__device__ __forceinline__ float softplus_fast(float x){
  float l = __logf(1.f + __expf(x));
  return (x > 20.f) ? x : l;
}

__device__ __forceinline__ void gload_lds16(const void* g, void* l){
  __builtin_amdgcn_global_load_lds((const __attribute__((address_space(1))) u32*)g,
                                   (__attribute__((address_space(3))) u32*)l, 16, 0, 0);
}

__global__ void k_sentinel(float* out){ out[0] = 1.2345e6f; }

__global__ void k_cast_bf16(const float* __restrict__ in, u16* __restrict__ out, int n){
  int i = (blockIdx.x*256 + threadIdx.x)*4;
  if (i >= n) return;
  float4 v = *(const float4*)(in + i);
  ushort4 o; o.x=f2bf(v.x); o.y=f2bf(v.y); o.z=f2bf(v.z); o.w=f2bf(v.w);
  *(ushort4*)(out + i) = o;
}

// W_a[i][j] = sum_c fc_w[i][c] * out_proj_w[c][j], padded to 64 rows (zeros), bf16
__global__ void k_make_wa(const float* __restrict__ fcw, const float* __restrict__ opw,
                          u16* __restrict__ wa){
  int j = blockIdx.x*256 + threadIdx.x;   // 0..1023
  int i = blockIdx.y;                     // 0..63
  float s = 0.f;
  if (i < 36){
    const float* fr = fcw + i*DM;
    #pragma unroll 8
    for (int k=0;k<DM;++k) s += fr[k]*opw[(size_t)k*DI + j];
  }
  wa[(size_t)i*DI + j] = f2bf(s);
}

// xz = f @ in_proj^T. 128x256 tile, BK=32, 512 thr (8 waves, 64x64 wave-tile),
// RING-3 pipeline with counted vmcnt (loads 2 tiles deep, never drained in steady state),
// chunk-transposed LDS [kchunk][row] (0 bank conflicts), XCD-grouped grid.
// grid 4096: d&7 = XCD, q=d>>3: row-group g = xcd+8*(q>>3), col-block cb = q&7.
__global__ __launch_bounds__(512) void k_gemm_xz(
  const u16* __restrict__ A, const u16* __restrict__ B,
  const float* __restrict__ convw, const float* __restrict__ convb,
  u16* __restrict__ xp, u16* __restrict__ zs)
{
  __shared__ u16 smem[36864];            // 72 KB: 3 x (A 4096 | B 8192) u16
  const int tid=threadIdx.x, wv=tid>>6, ln=tid&63;
  const int l15=ln&15, l4=ln>>4;
  const int d=blockIdx.x, xcd=d&7, q=d>>3;
  const int g = xcd + 8*(q>>3);          // 0..511 row-group (bijective)
  const int cb = q & 7;                  // 0..7 col-block
  const int r0 = g*128, c0 = cb*256;
  const int wm=wv>>2, wn=wv&3;           // 2M x 4N waves, wave tile 64x64
  f32x4 acc[4][4]={};

  // staging source addresses (chunk-transposed LDS layout via global permutation)
  const int arow=(wv&1)*64+ln, achk=wv>>1;          // A: row 0..127, k-chunk 0..3
  const int brow=(wv&3)*64+ln, bch=wv>>2;           // B: row 0..255, k-chunks {bch, bch+2}
  const u16* Ag  = A + (size_t)(r0+arow)*DM + achk*8;
  const u16* Bg0 = B + (size_t)(c0+brow)*DM + (bch+0)*8;
  const u16* Bg1 = B + (size_t)(c0+brow)*DM + (bch+2)*8;
  const int ldsA = wv*512;                           // u16 offsets within buf
  const int ldsB0 = wv*512, ldsB1 = 4096 + wv*512;

  auto STAGE=[&](int buf, int kt){
    const int k0 = kt*32;
    u16* Ad = smem + buf*12288;
    u16* Bd = Ad + 4096;
    gload_lds16(Ag  + k0, Ad + ldsA);
    gload_lds16(Bg0 + k0, Bd + ldsB0);
    gload_lds16(Bg1 + k0, Bd + ldsB1);
  };

  // fragment read offsets: A [chunk][row]: chunk*1024+row*8; B: chunk*2048+row*8
  int offA[4], offB[4];
  #pragma unroll
  for (int m=0;m<4;++m) offA[m] = l4*1024 + (wm*64 + m*16 + l15)*8;
  #pragma unroll
  for (int n=0;n<4;++n) offB[n] = l4*2048 + (wn*64 + n*16 + l15)*8;

  STAGE(0,0); STAGE(1,1);                // 6 loads/thread in flight
  #pragma clang loop unroll(disable)
  for (int t=0;t<16;++t){
    __builtin_amdgcn_sched_barrier(0);
    if (t<15) asm volatile("s_waitcnt vmcnt(3)" ::: "memory");  // tile t done; t+1 in flight
    else      asm volatile("s_waitcnt vmcnt(0)" ::: "memory");
    __builtin_amdgcn_s_barrier();
    __builtin_amdgcn_sched_barrier(0);
    if (t+2<16) STAGE((t+2)%3, t+2);     // overwrites buf (t-1)%3: readers passed barrier t
    const u16* Ac = smem + (t%3)*12288;
    const u16* Bc = Ac + 4096;
    bf16x8 af[4], bfr[4];
    #pragma unroll
    for (int m=0;m<4;++m) af[m]=*(const bf16x8*)(Ac + offA[m]);
    #pragma unroll
    for (int n=0;n<4;++n) bfr[n]=*(const bf16x8*)(Bc + offB[n]);
    #pragma unroll
    for (int m=0;m<4;++m)
      #pragma unroll
      for (int n=0;n<4;++n)
        acc[m][n]=__builtin_amdgcn_mfma_f32_16x16x32_bf16(af[m],bfr[n],acc[m][n],0,0,0);
    __builtin_amdgcn_sched_barrier(0);
  }
  __syncthreads();   // all waves done with buf0 (tile 15) before epilogue reuses smem

  // Epilogue: two half-restages of 128 cols through W[128][136] (stride 272B)
  const bool isx = (c0 < DI);
  u16* W = smem;
  #pragma unroll
  for (int ch=0; ch<2; ++ch){
    if ((wn>>1) == ch){
      #pragma unroll
      for (int n=0;n<4;++n){
        int tcol = (wn&1)*64 + n*16 + l15;          // 0..127 within half
        int gcol = c0 + ch*128 + tcol;
        float cw = isx ? convw[gcol*4+3] : 0.f;
        float cbv= isx ? convb[gcol]     : 0.f;
        #pragma unroll
        for (int m=0;m<4;++m){
          int trow = wm*64 + m*16 + l4*4;
          #pragma unroll
          for (int r=0;r<4;++r){
            float v = acc[m][n][r];
            float o = isx ? siluf(v*cw + cbv) : siluf(v);
            W[(trow+r)*136 + tcol] = f2bf(o);
          }
        }
      }
    }
    __syncthreads();
    const int orow = tid>>2, qq = tid&3;
    const u16* sp = W + orow*136 + qq*32;
    const int gc = c0 + ch*128 + qq*32;
    u16* dst = (isx ? xp : zs) + (size_t)(r0+orow)*DI + (isx ? gc : gc - DI);
    #pragma unroll
    for (int j=0;j<4;++j)
      ((int4*)dst)[j] = ((const int4*)sp)[j];
    __syncthreads();
  }
}

// 128-row tile x K=1024 GEMM against 64-row B, dbuf + swizzle.
// EPI=0: fused x_dbl epilogue -> dtb(bf16) + bc. EPI=1: out[t*36+j]=acc+fcb[j] (j<36)
template<int EPI>
__global__ __launch_bounds__(256) void k_gemm_n64(
  const u16* __restrict__ A, const u16* __restrict__ B,
  u16* __restrict__ dtb, float* __restrict__ bc,
  const float* __restrict__ fcb, float* __restrict__ out)
{
  __shared__ u16 smem[24576];             // 48 KB: As0|As1 (8192 each) | Bs0|Bs1 (4096 each)
  u16* SA = smem;
  u16* SB = smem + 16384;                 // +buf*4096
  const int tid=threadIdx.x, wv=tid>>6, ln=tid&63;
  const int l15=ln&15, l4=ln>>4, h=l15&7;
  const int r0=blockIdx.x*128;
  const int wm=wv>>1, wn=wv&1;
  const int sr=ln>>3, scs=((ln&7)^sr)*8;
  const int chk0=(l4^h)*8, chk1=((l4+4)^h)*8;
  const int rA=(wm*64+l15)*64, rB=(wn*32+l15)*64;
  f32x4 acc[4][2]={};

  auto STAGE=[&](int buf, int k0){
    u16* Ad = SA + buf*8192;
    u16* Bd = SB + buf*4096;
    #pragma unroll
    for (int it=0;it<4;++it){
      int c=wv*4+it;
      gload_lds16(A + (size_t)(r0 + c*8 + sr)*DI + k0 + scs, Ad + c*512);
    }
    #pragma unroll
    for (int it=0;it<2;++it){
      int c=wv*2+it;
      gload_lds16(B + (size_t)(c*8 + sr)*DI + k0 + scs, Bd + c*512);
    }
  };

  STAGE(0, 0);
  __syncthreads();
  __builtin_amdgcn_sched_barrier(0);
  int cur = 0;
  #pragma clang loop unroll(disable)
  for (int t=0;t<16;++t){
    if (t < 15) STAGE(cur^1, (t+1)*64);
    const u16* Ac = SA + cur*8192;
    const u16* Bc = SB + cur*4096;
    #pragma unroll
    for (int kk=0;kk<2;++kk){
      const int ch = kk ? chk1 : chk0;
      bf16x8 af[4], bfr[2];
      #pragma unroll
      for (int m=0;m<4;++m) af[m]=*(const bf16x8*)(Ac + rA + m*1024 + ch);
      #pragma unroll
      for (int n=0;n<2;++n) bfr[n]=*(const bf16x8*)(Bc + rB + n*1024 + ch);
      #pragma unroll
      for (int m=0;m<4;++m)
        #pragma unroll
        for (int n=0;n<2;++n)
          acc[m][n]=__builtin_amdgcn_mfma_f32_16x16x32_bf16(af[m],bfr[n],acc[m][n],0,0,0);
    }
    __syncthreads();
    __builtin_amdgcn_sched_barrier(0);
    cur ^= 1;
  }

  if (EPI==0){
    // restage fp32 x_dbl tile [128][68] -> emit dtb (cols 0..31, bf16) + bc (sum B*C)
    float* W = (float*)smem;
    #pragma unroll
    for (int n=0;n<2;++n){
      int j = wn*32 + n*16 + l15;
      #pragma unroll
      for (int m=0;m<4;++m){
        int trow = wm*64 + m*16 + l4*4;
        #pragma unroll
        for (int r=0;r<4;++r)
          W[(trow+r)*68 + j] = acc[m][n][r];
      }
    }
    __syncthreads();
    const int row = tid>>1, half = tid&1;
    const float* wr = W + row*68;
    if (half==0){
      u16* dst = dtb + (size_t)(r0+row)*32;
      #pragma unroll
      for (int qv=0;qv<4;++qv){
        bf16x8 o;
        #pragma unroll
        for (int e=0;e<8;++e) o[e] = (short)f2bf(wr[qv*8+e]);
        *(bf16x8*)(dst + qv*8) = o;
      }
    } else {
      float s=0.f;
      #pragma unroll
      for (int e=0;e<16;++e) s += wr[32+e]*wr[48+e];
      bc[r0+row] = s;
    }
  } else {
    #pragma unroll
    for (int n=0;n<2;++n){
      int j = wn*32 + n*16 + l15;   // 0..63
      #pragma unroll
      for (int m=0;m<4;++m){
        #pragma unroll
        for (int r=0;r<4;++r){
          int t = r0 + wm*64 + m*16 + l4*4 + r;
          if (j < 36) out[(size_t)t*36 + j] = acc[m][n][r] + fcb[j];
        }
      }
    }
  }
}

// delta GEMM (K=32) + fused w=softplus*bc+D in-fragment, LDS-restaged (bf16) epilogue:
// vectorized xp/zy int4 loads, y stored int4 in place. grid (8, 512).
__global__ __launch_bounds__(256) void k_delta_y(
  const u16* __restrict__ dtb, const u16* __restrict__ Bw,
  const float* __restrict__ dpb, const float* __restrict__ Dv,
  const float* __restrict__ bc,
  const u16* __restrict__ xp, u16* __restrict__ zy)
{
  __shared__ u16 smem[17408];            // 34.8 KB: GEMM phase As(4096)|Bs(4096); epi phase W[128][136]
  u16* As = smem;
  u16* Bs = smem + 4096;
  const int tid=threadIdx.x, wv=tid>>6, ln=tid&63;
  const int l15=ln&15, l4=ln>>4;
  const int c0=blockIdx.x*128, r0=blockIdx.y*128;
  const int wm=wv>>1, wn=wv&1;
  const int sr=ln>>2, sc=(ln&3)*8;   // 16 rows/chunk, 4 lanes/row
  #pragma unroll
  for (int it=0;it<2;++it){
    int c=wv*2+it;
    gload_lds16(dtb + (size_t)(r0 + c*16 + sr)*32 + sc, As + c*512);
  }
  #pragma unroll
  for (int it=0;it<2;++it){
    int c=wv*2+it;
    gload_lds16(Bw + (size_t)(c0 + c*16 + sr)*32 + sc, Bs + c*512);
  }
  __syncthreads();
  __builtin_amdgcn_sched_barrier(0);
  f32x4 acc[4][4]={};
  bf16x8 af[4], bfr[4];
  #pragma unroll
  for (int m=0;m<4;++m) af[m]=*(const bf16x8*)(As + (wm*64+m*16+l15)*32 + l4*8);
  #pragma unroll
  for (int n=0;n<4;++n) bfr[n]=*(const bf16x8*)(Bs + (wn*64+n*16+l15)*32 + l4*8);
  #pragma unroll
  for (int m=0;m<4;++m)
    #pragma unroll
    for (int n=0;n<4;++n)
      acc[m][n]=__builtin_amdgcn_mfma_f32_16x16x32_bf16(af[m],bfr[n],acc[m][n],0,0,0);
  __syncthreads();   // all waves done reading As/Bs before W overwrites them
  // in-fragment: w = softplus(acc + dpb[j]) * bc[t] + D[j], restage bf16 to W[128][136]
  u16* W = smem;
  #pragma unroll
  for (int n=0;n<4;++n){
    int tcol = wn*64 + n*16 + l15;
    int j = c0 + tcol;
    float dpbj = dpb[j], Dj = Dv[j];
    #pragma unroll
    for (int m=0;m<4;++m){
      int trow = wm*64 + m*16 + l4*4;
      #pragma unroll
      for (int r=0;r<4;++r){
        float delta = softplus_fast(acc[m][n][r] + dpbj);
        float w = delta*bc[r0 + trow + r] + Dj;
        W[(trow+r)*136 + tcol] = f2bf(w);
      }
    }
  }
  __syncthreads();
  // vectorized finish: each thread owns a contiguous 64-col half-row
  const int row = tid>>1, half = tid&1;
  const u16* wp = W + row*136 + half*64;
  const size_t gbase = (size_t)(r0 + row)*DI + c0 + half*64;
  const u16* xpp = xp + gbase;
  u16* zp = zy + gbase;
  #pragma unroll
  for (int q=0;q<8;++q){
    bf16x8 wv8 = *(const bf16x8*)(wp + q*8);
    bf16x8 xv  = *(const bf16x8*)(xpp + q*8);
    bf16x8 zv  = *(const bf16x8*)(zp + q*8);
    bf16x8 ov;
    #pragma unroll
    for (int e=0;e<8;++e){
      float y = bf2f((u16)wv8[e]) * bf2f((u16)xv[e]) * bf2f((u16)zv[e]);
      ov[e] = (short)f2bf(y);
    }
    *(bf16x8*)(zp + q*8) = ov;
  }
}

extern "C" void kernel_launch(void* const* d_in, const int* in_sizes, int n_in,
                              void* d_out, int out_size, void* d_ws, size_t ws_size,
                              hipStream_t stream){
  const float* f      = (const float*)d_in[0];
  const float* inpw   = (const float*)d_in[1];
  const float* convw  = (const float*)d_in[2];
  const float* convb  = (const float*)d_in[3];
  const float* xprojw = (const float*)d_in[4];
  const float* dtpw   = (const float*)d_in[5];
  const float* dtpb   = (const float*)d_in[6];
  const float* Dv     = (const float*)d_in[8];
  const float* opw    = (const float*)d_in[9];
  const float* fcw    = (const float*)d_in[10];
  const float* fcb    = (const float*)d_in[11];
  float* out = (float*)d_out;

  char* ws = (char*)d_ws;
  size_t off = 0;
  auto alloc = [&](size_t sz)->void*{ void* p = ws + off; off += (sz + 255) & ~(size_t)255; return p; };
  u16*   fbf = (u16*)  alloc((size_t)NTOK*DM*2);
  u16*   xp  = (u16*)  alloc((size_t)NTOK*DI*2);
  u16*   zy  = (u16*)  alloc((size_t)NTOK*DI*2);
  u16*   dtb = (u16*)  alloc((size_t)NTOK*32*2);
  float* bc  = (float*)alloc((size_t)NTOK*4);
  u16*   ipw = (u16*)  alloc((size_t)2048*512*2);
  u16*   xpw = (u16*)  alloc((size_t)64*1024*2);
  u16*   dpw = (u16*)  alloc((size_t)1024*32*2);
  u16*   wa  = (u16*)  alloc((size_t)64*1024*2);
  if (off > ws_size){ k_sentinel<<<1,1,0,stream>>>(out); return; }

  k_cast_bf16<<<dim3((NTOK*DM/4)/256),256,0,stream>>>(f, fbf, NTOK*DM);
  k_cast_bf16<<<dim3((2048*512/4)/256),256,0,stream>>>(inpw, ipw, 2048*512);
  k_cast_bf16<<<dim3((64*1024/4)/256),256,0,stream>>>(xprojw, xpw, 64*1024);
  k_cast_bf16<<<dim3((1024*32/4)/256),256,0,stream>>>(dtpw, dpw, 1024*32);
  k_make_wa<<<dim3(4,64),256,0,stream>>>(fcw, opw, wa);

  k_gemm_xz<<<dim3(4096),512,0,stream>>>(fbf, ipw, convw, convb, xp, zy);
  k_gemm_n64<0><<<dim3(512),256,0,stream>>>(xp, xpw, dtb, bc, nullptr, nullptr);
  k_delta_y<<<dim3(8,512),256,0,stream>>>(dtb, dpw, dtpb, Dv, bc, xp, zy);
  k_gemm_n64<1><<<dim3(512),256,0,stream>>>(zy, wa, nullptr, nullptr, fcb, out);
}